// Round 1
// baseline (6237.986 us; speedup 1.0000x reference)
//
#include <hip/hip_runtime.h>
#include <math.h>

#define NB 4
#define TT 2048
#define CC 2048
#define HH 16
#define DD 128
#define N3 6144
#define MM 8192   // NB*TT

constexpr float SCALE_QK  = 0.08838834764831843f;   // 1/sqrt(128)
constexpr float NEG_ALPHA = -0.20503692777194262f;  // -2*ln(500000)/128

// ---------------------------------------------------------------------------
// Kernel 1: QKV GEMM + RoPE epilogue.
// X[8192][2048] @ Wqkv[2048][6144] -> q,k (RoPE'd), v in [B][H][T][D] layout.
// 128x128 tile, BK=16, 256 threads, 8x8 micro-tile (cols split {tx*4, 64+tx*4}).
// ---------------------------------------------------------------------------
__global__ __launch_bounds__(256) void qkv_rope_gemm(
    const float* __restrict__ X, const float* __restrict__ W,
    float* __restrict__ Qo, float* __restrict__ Ko, float* __restrict__ Vo)
{
    constexpr int BM = 128, BK = 16;
    __shared__ float As[BK][BM];        // transposed A tile
    __shared__ float Bs[BK][128 + 4];   // +4 pad: 2-way-max bank conflicts

    const int tid = threadIdx.x;
    const int ty = tid >> 4, tx = tid & 15;
    const int m0 = blockIdx.x * BM;
    const int n0 = blockIdx.y * 128;

    const int am = tid >> 1;            // A row within tile (2 threads/row)
    const int ak = (tid & 1) << 3;      // k offset 0 or 8
    const int bk = tid >> 4;            // B row within tile
    const int bn = (tid & 15) << 3;     // B col offset

    const float* aptr = X + (size_t)(m0 + am) * CC + ak;
    const float* bptr = W + (size_t)bk * N3 + n0 + bn;

    float acc[8][8];
    #pragma unroll
    for (int i = 0; i < 8; ++i)
        #pragma unroll
        for (int j = 0; j < 8; ++j) acc[i][j] = 0.f;

    for (int k0 = 0; k0 < CC; k0 += BK) {
        float4 a0 = *(const float4*)(aptr);
        float4 a1 = *(const float4*)(aptr + 4);
        float4 b0 = *(const float4*)(bptr);
        float4 b1 = *(const float4*)(bptr + 4);
        aptr += BK;
        bptr += (size_t)BK * N3;
        __syncthreads();   // previous iteration's LDS reads complete
        As[ak+0][am] = a0.x; As[ak+1][am] = a0.y; As[ak+2][am] = a0.z; As[ak+3][am] = a0.w;
        As[ak+4][am] = a1.x; As[ak+5][am] = a1.y; As[ak+6][am] = a1.z; As[ak+7][am] = a1.w;
        *(float4*)&Bs[bk][bn]     = b0;
        *(float4*)&Bs[bk][bn + 4] = b1;
        __syncthreads();
        #pragma unroll
        for (int kk = 0; kk < BK; ++kk) {
            float4 a_0 = *(const float4*)&As[kk][ty*8];
            float4 a_1 = *(const float4*)&As[kk][ty*8 + 4];
            float4 b_0 = *(const float4*)&Bs[kk][tx*4];
            float4 b_1 = *(const float4*)&Bs[kk][64 + tx*4];
            float av[8] = {a_0.x,a_0.y,a_0.z,a_0.w,a_1.x,a_1.y,a_1.z,a_1.w};
            float bv[8] = {b_0.x,b_0.y,b_0.z,b_0.w,b_1.x,b_1.y,b_1.z,b_1.w};
            #pragma unroll
            for (int i = 0; i < 8; ++i)
                #pragma unroll
                for (int j = 0; j < 8; ++j)
                    acc[i][j] = fmaf(av[i], bv[j], acc[i][j]);
        }
    }

    // epilogue: the 128-wide n-tile is exactly one head of one of q/k/v
    const int sec = n0 >> 11;          // 0=q 1=k 2=v
    const int h   = (n0 & 2047) >> 7;
    float* dst = (sec == 0) ? Qo : (sec == 1) ? Ko : Vo;

    #pragma unroll
    for (int i = 0; i < 8; ++i) {
        const int m = m0 + ty*8 + i;
        const int b = m >> 11;         // / T
        const int t = m & 2047;        // % T
        float* rowp = dst + ((size_t)(b*HH + h)*TT + t) * DD;
        #pragma unroll
        for (int g = 0; g < 2; ++g) {
            const int d0 = g*64 + tx*4;
            float v0 = acc[i][g*4+0], v1 = acc[i][g*4+1];
            float v2 = acc[i][g*4+2], v3 = acc[i][g*4+3];
            if (sec < 2) {   // RoPE on q,k: pairs (d0,d0+1),(d0+2,d0+3)
                const int p0 = d0 >> 1;
                float s0, c0, s1, c1;
                sincosf((float)t * expf((float)p0       * NEG_ALPHA), &s0, &c0);
                sincosf((float)t * expf((float)(p0 + 1) * NEG_ALPHA), &s1, &c1);
                float r0 = v0*c0 - v1*s0;
                float r1 = v1*c0 + v0*s0;
                float r2 = v2*c1 - v3*s1;
                float r3 = v3*c1 + v2*s1;
                v0 = r0; v1 = r1; v2 = r2; v3 = r3;
            }
            *(float4*)(rowp + d0) = make_float4(v0, v1, v2, v3);
        }
    }
}

// ---------------------------------------------------------------------------
// Kernel 2: causal flash attention, fp32. One block = (b,h, 64-row q-tile).
// 64x64 S tiles, online softmax, LDS-staged Q/K/V/P with conflict-safe strides.
// ---------------------------------------------------------------------------
__global__ __launch_bounds__(256) void attn_fwd(
    const float* __restrict__ Q, const float* __restrict__ K,
    const float* __restrict__ V, float* __restrict__ Y)
{
    __shared__ float Qs[64][132];
    __shared__ float Ks[64][132];
    __shared__ float Vs[64][132];
    __shared__ float Ps[64][68];

    const int tid = threadIdx.x;
    const int ty = tid >> 4, tx = tid & 15;
    const int qt = blockIdx.x;
    const int bh = blockIdx.y;
    const int b = bh >> 4, h = bh & 15;

    const float* Qp = Q + (size_t)bh * TT * DD + (size_t)qt * 64 * DD;
    const float* Kp = K + (size_t)bh * TT * DD;
    const float* Vp = V + (size_t)bh * TT * DD;

    {   // load Q tile (64x128): 4 threads per row, 32 floats each
        const int r  = tid >> 2;
        const int d0 = (tid & 3) << 5;
        #pragma unroll
        for (int u = 0; u < 8; ++u)
            *(float4*)&Qs[r][d0 + u*4] = *(const float4*)(Qp + r*DD + d0 + u*4);
    }

    float m_r[4], l_r[4], o[4][8];
    #pragma unroll
    for (int i = 0; i < 4; ++i) {
        m_r[i] = -1e30f; l_r[i] = 0.f;
        #pragma unroll
        for (int c = 0; c < 8; ++c) o[i][c] = 0.f;
    }

    const int q0 = qt * 64;
    for (int kt = 0; kt <= qt; ++kt) {
        __syncthreads();   // prev iter LDS reads done (also publishes Qs on iter 0)
        {
            const int r  = tid >> 2;
            const int d0 = (tid & 3) << 5;
            const float* kr = Kp + (size_t)(kt*64 + r) * DD + d0;
            const float* vr = Vp + (size_t)(kt*64 + r) * DD + d0;
            #pragma unroll
            for (int u = 0; u < 8; ++u) {
                *(float4*)&Ks[r][d0 + u*4] = *(const float4*)(kr + u*4);
                *(float4*)&Vs[r][d0 + u*4] = *(const float4*)(vr + u*4);
            }
        }
        __syncthreads();

        // S[4][4]: rows ty*4+i, cols j*16+tx
        float s[4][4];
        #pragma unroll
        for (int i = 0; i < 4; ++i)
            #pragma unroll
            for (int j = 0; j < 4; ++j) s[i][j] = 0.f;

        for (int d0 = 0; d0 < DD; d0 += 4) {
            float4 qv[4], kv[4];
            #pragma unroll
            for (int i = 0; i < 4; ++i) qv[i] = *(const float4*)&Qs[ty*4 + i][d0];
            #pragma unroll
            for (int j = 0; j < 4; ++j) kv[j] = *(const float4*)&Ks[j*16 + tx][d0];
            #pragma unroll
            for (int i = 0; i < 4; ++i)
                #pragma unroll
                for (int j = 0; j < 4; ++j) {
                    s[i][j] = fmaf(qv[i].x, kv[j].x, s[i][j]);
                    s[i][j] = fmaf(qv[i].y, kv[j].y, s[i][j]);
                    s[i][j] = fmaf(qv[i].z, kv[j].z, s[i][j]);
                    s[i][j] = fmaf(qv[i].w, kv[j].w, s[i][j]);
                }
        }

        // mask + online softmax (row reduce across the 16 tx lanes)
        #pragma unroll
        for (int i = 0; i < 4; ++i) {
            const int qg = q0 + ty*4 + i;
            float rm = -1e30f;
            #pragma unroll
            for (int j = 0; j < 4; ++j) {
                const int kg = kt*64 + j*16 + tx;
                float sv = s[i][j] * SCALE_QK;
                sv = (kg > qg) ? -1e30f : sv;
                s[i][j] = sv;
                rm = fmaxf(rm, sv);
            }
            rm = fmaxf(rm, __shfl_xor(rm, 1));
            rm = fmaxf(rm, __shfl_xor(rm, 2));
            rm = fmaxf(rm, __shfl_xor(rm, 4));
            rm = fmaxf(rm, __shfl_xor(rm, 8));
            const float mn    = fmaxf(m_r[i], rm);
            const float alpha = expf(m_r[i] - mn);
            m_r[i] = mn;
            float rs = 0.f;
            #pragma unroll
            for (int j = 0; j < 4; ++j) {
                float p = expf(s[i][j] - mn);
                s[i][j] = p;
                rs += p;
            }
            rs += __shfl_xor(rs, 1);
            rs += __shfl_xor(rs, 2);
            rs += __shfl_xor(rs, 4);
            rs += __shfl_xor(rs, 8);
            l_r[i] = l_r[i] * alpha + rs;
            #pragma unroll
            for (int c = 0; c < 8; ++c) o[i][c] *= alpha;
            #pragma unroll
            for (int j = 0; j < 4; ++j) Ps[ty*4 + i][j*16 + tx] = s[i][j];
        }
        __syncthreads();

        // O += P @ V : rows ty*4+i, cols {tx*4, 64+tx*4}
        for (int kk0 = 0; kk0 < 64; kk0 += 4) {
            float pb[4][4];
            #pragma unroll
            for (int i = 0; i < 4; ++i) {
                float4 p4 = *(const float4*)&Ps[ty*4 + i][kk0];
                pb[i][0] = p4.x; pb[i][1] = p4.y; pb[i][2] = p4.z; pb[i][3] = p4.w;
            }
            #pragma unroll
            for (int u = 0; u < 4; ++u) {
                float4 va = *(const float4*)&Vs[kk0 + u][tx*4];
                float4 vb = *(const float4*)&Vs[kk0 + u][64 + tx*4];
                #pragma unroll
                for (int i = 0; i < 4; ++i) {
                    const float p = pb[i][u];
                    o[i][0] = fmaf(p, va.x, o[i][0]);
                    o[i][1] = fmaf(p, va.y, o[i][1]);
                    o[i][2] = fmaf(p, va.z, o[i][2]);
                    o[i][3] = fmaf(p, va.w, o[i][3]);
                    o[i][4] = fmaf(p, vb.x, o[i][4]);
                    o[i][5] = fmaf(p, vb.y, o[i][5]);
                    o[i][6] = fmaf(p, vb.z, o[i][6]);
                    o[i][7] = fmaf(p, vb.w, o[i][7]);
                }
            }
        }
    }

    // normalize + write y in [B][T][C] layout (col = h*128 + d)
    #pragma unroll
    for (int i = 0; i < 4; ++i) {
        const int t = q0 + ty*4 + i;
        const float inv = 1.f / l_r[i];
        float* yp = Y + (size_t)(b*TT + t) * CC + h*DD;
        *(float4*)(yp + tx*4)      = make_float4(o[i][0]*inv, o[i][1]*inv, o[i][2]*inv, o[i][3]*inv);
        *(float4*)(yp + 64 + tx*4) = make_float4(o[i][4]*inv, o[i][5]*inv, o[i][6]*inv, o[i][7]*inv);
    }
}

// ---------------------------------------------------------------------------
// Kernel 3: output projection GEMM. y[8192][2048] @ Wproj[2048][2048] -> out.
// ---------------------------------------------------------------------------
__global__ __launch_bounds__(256) void proj_gemm(
    const float* __restrict__ X, const float* __restrict__ W,
    float* __restrict__ Out)
{
    constexpr int BM = 128, BK = 16;
    __shared__ float As[BK][BM];
    __shared__ float Bs[BK][128 + 4];

    const int tid = threadIdx.x;
    const int ty = tid >> 4, tx = tid & 15;
    const int m0 = blockIdx.x * BM;
    const int n0 = blockIdx.y * 128;

    const int am = tid >> 1;
    const int ak = (tid & 1) << 3;
    const int bk = tid >> 4;
    const int bn = (tid & 15) << 3;

    const float* aptr = X + (size_t)(m0 + am) * CC + ak;
    const float* bptr = W + (size_t)bk * CC + n0 + bn;

    float acc[8][8];
    #pragma unroll
    for (int i = 0; i < 8; ++i)
        #pragma unroll
        for (int j = 0; j < 8; ++j) acc[i][j] = 0.f;

    for (int k0 = 0; k0 < CC; k0 += BK) {
        float4 a0 = *(const float4*)(aptr);
        float4 a1 = *(const float4*)(aptr + 4);
        float4 b0 = *(const float4*)(bptr);
        float4 b1 = *(const float4*)(bptr + 4);
        aptr += BK;
        bptr += (size_t)BK * CC;
        __syncthreads();
        As[ak+0][am] = a0.x; As[ak+1][am] = a0.y; As[ak+2][am] = a0.z; As[ak+3][am] = a0.w;
        As[ak+4][am] = a1.x; As[ak+5][am] = a1.y; As[ak+6][am] = a1.z; As[ak+7][am] = a1.w;
        *(float4*)&Bs[bk][bn]     = b0;
        *(float4*)&Bs[bk][bn + 4] = b1;
        __syncthreads();
        #pragma unroll
        for (int kk = 0; kk < BK; ++kk) {
            float4 a_0 = *(const float4*)&As[kk][ty*8];
            float4 a_1 = *(const float4*)&As[kk][ty*8 + 4];
            float4 b_0 = *(const float4*)&Bs[kk][tx*4];
            float4 b_1 = *(const float4*)&Bs[kk][64 + tx*4];
            float av[8] = {a_0.x,a_0.y,a_0.z,a_0.w,a_1.x,a_1.y,a_1.z,a_1.w};
            float bv[8] = {b_0.x,b_0.y,b_0.z,b_0.w,b_1.x,b_1.y,b_1.z,b_1.w};
            #pragma unroll
            for (int i = 0; i < 8; ++i)
                #pragma unroll
                for (int j = 0; j < 8; ++j)
                    acc[i][j] = fmaf(av[i], bv[j], acc[i][j]);
        }
    }

    #pragma unroll
    for (int i = 0; i < 8; ++i) {
        const int m = m0 + ty*8 + i;
        float* rowp = Out + (size_t)m * CC + n0;
        *(float4*)(rowp + tx*4)      = make_float4(acc[i][0], acc[i][1], acc[i][2], acc[i][3]);
        *(float4*)(rowp + 64 + tx*4) = make_float4(acc[i][4], acc[i][5], acc[i][6], acc[i][7]);
    }
}

// ---------------------------------------------------------------------------
extern "C" void kernel_launch(void* const* d_in, const int* in_sizes, int n_in,
                              void* d_out, int out_size, void* d_ws, size_t ws_size,
                              hipStream_t stream)
{
    const float* X     = (const float*)d_in[0];
    const float* Wqkv  = (const float*)d_in[1];
    const float* Wproj = (const float*)d_in[2];
    float* out = (float*)d_out;

    const size_t QSZ = (size_t)NB * HH * TT * DD;   // 16,777,216 elems
    float* q = (float*)d_ws;
    float* k = q + QSZ;
    float* v = k + QSZ;
    float* y = v + QSZ;          // total ws use: 256 MiB

    dim3 g1(MM / 128, N3 / 128);     // 64 x 48
    qkv_rope_gemm<<<g1, 256, 0, stream>>>(X, Wqkv, q, k, v);

    dim3 g2(TT / 64, NB * HH);       // 32 x 64
    attn_fwd<<<g2, 256, 0, stream>>>(q, k, v, y);

    dim3 g3(MM / 128, CC / 128);     // 64 x 16
    proj_gemm<<<g3, 256, 0, stream>>>(y, Wproj, out);
}

// Round 2
// 1404.576 us; speedup vs baseline: 4.4412x; 4.4412x over previous
//
#include <hip/hip_runtime.h>
#include <math.h>

#define NB 4
#define TT 2048
#define CC 2048
#define HH 16
#define DD 128
#define N3 6144
#define MM 8192   // NB*TT
#define BH 64     // NB*HH

typedef short bf8 __attribute__((ext_vector_type(8)));        // 8 bf16 (4 VGPR)
typedef float f32x4 __attribute__((ext_vector_type(4)));
typedef unsigned short u16x8 __attribute__((ext_vector_type(8)));
typedef unsigned short u16;

constexpr float SCALE_QK  = 0.08838834764831843f;   // 1/sqrt(128)
constexpr float NEG_ALPHA = -0.20503692777194262f;  // -2*ln(500000)/128

__device__ __forceinline__ u16 f2bf(float x) {                 // RTNE f32->bf16
    unsigned int u = __float_as_uint(x);
    u += 0x7fffu + ((u >> 16) & 1u);
    return (u16)(u >> 16);
}
__device__ __forceinline__ float bf2f(u16 h) { return __uint_as_float(((unsigned int)h) << 16); }

__device__ __forceinline__ void gl_lds16(const u16* g, u16* l) {
    __builtin_amdgcn_global_load_lds(reinterpret_cast<const unsigned int*>(g),
                                     reinterpret_cast<unsigned int*>(l), 16, 0, 0);
}
__device__ __forceinline__ f32x4 MFMA(bf8 a, bf8 b, f32x4 c) {
    return __builtin_amdgcn_mfma_f32_16x16x32_bf16(a, b, c, 0, 0, 0);
}

// ---------------------------------------------------------------------------
// RoPE table: tab[t][p] = {cos, sin}(t * base^(-2p/128)), 2048 x 64 x 2 f32.
// ---------------------------------------------------------------------------
__global__ void rope_tab_k(float* __restrict__ tab) {
    int t = blockIdx.x, p = threadIdx.x;
    float inv = expf((float)p * NEG_ALPHA);
    float s, c;
    sincosf((float)t * inv, &s, &c);
    tab[(t * 64 + p) * 2]     = c;
    tab[(t * 64 + p) * 2 + 1] = s;
}

// ---------------------------------------------------------------------------
// Elementwise split fp32 -> bf16 hi + bf16 lo (same layout).
// ---------------------------------------------------------------------------
__global__ __launch_bounds__(256) void split_x_k(const float* __restrict__ X,
                                                 u16* __restrict__ H, u16* __restrict__ L) {
    size_t base = ((size_t)blockIdx.x * 256 + threadIdx.x) * 16;
    #pragma unroll
    for (int g = 0; g < 2; ++g) {
        u16x8 hv, lv;
        #pragma unroll
        for (int j = 0; j < 8; j += 4) {
            float4 a = *(const float4*)(X + base + g * 8 + j);
            float xs[4] = {a.x, a.y, a.z, a.w};
            #pragma unroll
            for (int q = 0; q < 4; ++q) {
                u16 h = f2bf(xs[q]);
                hv[j + q] = h;
                lv[j + q] = f2bf(xs[q] - bf2f(h));
            }
        }
        *(u16x8*)&H[base + g * 8] = hv;
        *(u16x8*)&L[base + g * 8] = lv;
    }
}

// ---------------------------------------------------------------------------
// Split + transpose: W[Kd][Nd] fp32 -> OH/OL[Nd][Kd] bf16.
// ---------------------------------------------------------------------------
__global__ __launch_bounds__(256) void splitT_k(const float* __restrict__ W,
                                                u16* __restrict__ OH, u16* __restrict__ OL,
                                                int Kd, int Nd) {
    __shared__ float tile[64][68];
    int k0 = blockIdx.x * 64, n0 = blockIdx.y * 64;
    {
        int r = threadIdx.x >> 2, cg = threadIdx.x & 3;
        const float* src = W + (size_t)(k0 + r) * Nd + n0 + cg * 16;
        #pragma unroll
        for (int j = 0; j < 4; ++j)
            *(float4*)&tile[r][cg * 16 + j * 4] = *(const float4*)(src + j * 4);
    }
    __syncthreads();
    int nl = threadIdx.x >> 2, kg = threadIdx.x & 3;
    u16x8 hv[2], lv[2];
    #pragma unroll
    for (int j = 0; j < 16; ++j) {
        float v = tile[kg * 16 + j][nl];
        u16 h = f2bf(v);
        hv[j >> 3][j & 7] = h;
        lv[j >> 3][j & 7] = f2bf(v - bf2f(h));
    }
    size_t off = (size_t)(n0 + nl) * Kd + k0 + kg * 16;
    *(u16x8*)&OH[off]     = hv[0];
    *(u16x8*)&OH[off + 8] = hv[1];
    *(u16x8*)&OL[off]     = lv[0];
    *(u16x8*)&OL[off + 8] = lv[1];
}

// ---------------------------------------------------------------------------
// 3-pass split-bf16 MFMA GEMM: C = Ah*Bh + Ah*Bl + Al*Bh (fp32 acc).
// A[M][Kd] planes, B stored transposed [N][Kd] planes. 128x128 tile, BK=32,
// 4 waves (2x2), 4x4 16x16x32 frags/wave. LDS XOR-swizzle via pre-swizzled
// global source (global_load_lds dest must stay linear).
// MODE 0: QKV epilogue (rope via tab; Q hi/lo, K bf16, V transposed [bh][d][t]).
// MODE 1: plain fp32 store.
// ---------------------------------------------------------------------------
template<int MODE>
__global__ __launch_bounds__(256) void gemm3(
    const u16* __restrict__ Ah, const u16* __restrict__ Al,
    const u16* __restrict__ Bhp, const u16* __restrict__ Blp,
    u16* __restrict__ Qh, u16* __restrict__ Ql,
    u16* __restrict__ Kbo, u16* __restrict__ Vto,
    const float* __restrict__ tab, float* __restrict__ Out)
{
    __shared__ u16 SM[128 * 64 * 2];          // As = SM, Bs = SM+8192; 32 KiB
    u16* As = SM;
    u16* Bs = SM + 8192;
    const int Kd = 2048;

    const int tid = threadIdx.x;
    const int w = tid >> 6, ln = tid & 63;
    const int lo4 = ln & 15, hi4 = ln >> 4;
    const int wr = w >> 1, wc = w & 1;
    const int m0 = blockIdx.x * 128, n0 = blockIdx.y * 128;

    f32x4 acc[4][4];
    #pragma unroll
    for (int i = 0; i < 4; ++i)
        #pragma unroll
        for (int j = 0; j < 4; ++j) acc[i][j] = (f32x4){0.f, 0.f, 0.f, 0.f};

    for (int k0 = 0; k0 < Kd; k0 += 32) {
        __syncthreads();
        #pragma unroll
        for (int i = 0; i < 4; ++i) {
            int L = i * 4096 + tid * 16;       // byte offset in 16 KiB
            int r = L >> 7;                    // row (128 B rows: 4 hi + 4 lo chunks)
            int c = (L >> 4) & 7;
            int cs = c ^ (r & 7);              // pre-swizzled source chunk
            const u16* sa = (cs & 4) ? Al : Ah;
            gl_lds16(sa + (size_t)(m0 + r) * Kd + k0 + (cs & 3) * 8, &As[L >> 1]);
            const u16* sb = (cs & 4) ? Blp : Bhp;
            gl_lds16(sb + (size_t)(n0 + r) * Kd + k0 + (cs & 3) * 8, &Bs[L >> 1]);
        }
        __syncthreads();

        bf8 a_h[4], a_l[4], b_h[4], b_l[4];
        #pragma unroll
        for (int mf = 0; mf < 4; ++mf) {
            int r = wr * 64 + mf * 16 + lo4, s = r & 7;
            a_h[mf] = *(const bf8*)&As[r * 64 + ((hi4 ^ s) * 8)];
            a_l[mf] = *(const bf8*)&As[r * 64 + (((4 + hi4) ^ s) * 8)];
        }
        #pragma unroll
        for (int nf = 0; nf < 4; ++nf) {
            int r = wc * 64 + nf * 16 + lo4, s = r & 7;
            b_h[nf] = *(const bf8*)&Bs[r * 64 + ((hi4 ^ s) * 8)];
            b_l[nf] = *(const bf8*)&Bs[r * 64 + (((4 + hi4) ^ s) * 8)];
        }
        #pragma unroll
        for (int mf = 0; mf < 4; ++mf)
            #pragma unroll
            for (int nf = 0; nf < 4; ++nf) {
                acc[mf][nf] = MFMA(a_h[mf], b_h[nf], acc[mf][nf]);
                acc[mf][nf] = MFMA(a_h[mf], b_l[nf], acc[mf][nf]);
                acc[mf][nf] = MFMA(a_l[mf], b_h[nf], acc[mf][nf]);
            }
    }

    if (MODE == 1) {
        #pragma unroll
        for (int mf = 0; mf < 4; ++mf)
            #pragma unroll
            for (int r = 0; r < 4; ++r) {
                int m = m0 + wr * 64 + mf * 16 + hi4 * 4 + r;
                float* rowp = Out + (size_t)m * CC + n0 + wc * 64;
                #pragma unroll
                for (int nf = 0; nf < 4; ++nf)
                    rowp[nf * 16 + lo4] = acc[mf][nf][r];
            }
        return;
    }

    // MODE 0: qkv epilogue. 128-wide n-tile == one head of one of q/k/v.
    const int sec = n0 >> 11;                  // 0=q 1=k 2=v
    const int hh = (n0 >> 7) & 15;
    if (sec < 2) {
        #pragma unroll
        for (int mf = 0; mf < 4; ++mf)
            #pragma unroll
            for (int r = 0; r < 4; ++r) {
                int m = m0 + wr * 64 + mf * 16 + hi4 * 4 + r;
                int t = m & 2047, b = m >> 11;
                #pragma unroll
                for (int nf = 0; nf < 4; ++nf) {
                    int hc = wc * 64 + nf * 16 + lo4;
                    float v = acc[mf][nf][r];
                    float o = __shfl_xor(v, 1);
                    const float2 cs2 = *(const float2*)&tab[(((size_t)t << 6) + (hc >> 1)) * 2];
                    float rv = (ln & 1) ? (v * cs2.x + o * cs2.y)
                                        : (v * cs2.x - o * cs2.y);
                    size_t off = (((size_t)(b * HH + hh)) * TT + t) * DD + hc;
                    if (sec == 0) {
                        rv *= SCALE_QK;
                        u16 h = f2bf(rv);
                        Qh[off] = h;
                        Ql[off] = f2bf(rv - bf2f(h));
                    } else {
                        Kbo[off] = f2bf(rv);
                    }
                }
            }
    } else {
        // V: bf16, transposed to [bh][d][t] via LDS tile (reuse SM: 128x128 u16).
        __syncthreads();                       // all waves done reading As/Bs
        #pragma unroll
        for (int mf = 0; mf < 4; ++mf)
            #pragma unroll
            for (int r = 0; r < 4; ++r) {
                int ml = wr * 64 + mf * 16 + hi4 * 4 + r;
                #pragma unroll
                for (int nf = 0; nf < 4; ++nf) {
                    int d = wc * 64 + nf * 16 + lo4;
                    SM[ml * 128 + d] = f2bf(acc[mf][nf][r]);
                }
            }
        __syncthreads();
        int d = tid >> 1, hf = tid & 1;
        int b = m0 >> 11, t0 = m0 & 2047;
        size_t base = (((size_t)(b * HH + hh)) * DD + d) * TT + t0 + hf * 64;
        #pragma unroll
        for (int g = 0; g < 8; ++g) {
            u16x8 vv;
            #pragma unroll
            for (int j = 0; j < 8; ++j) vv[j] = SM[(hf * 64 + g * 8 + j) * 128 + d];
            *(u16x8*)&Vto[base + g * 8] = vv;
        }
    }
}

// ---------------------------------------------------------------------------
// Flash attention, bf16 MFMA. Block = (qtile 64 rows, bh). 4 waves x 16 q-rows.
// Q hi/lo (2x QK mfma), K/P/V single bf16. fp32 online softmax.
// K LDS [64][128], Vt LDS [128][64] (from pre-transposed V), all XOR-swizzled.
// Output y written as bf16 hi/lo planes (row-major [M][C]) for the proj GEMM.
// ---------------------------------------------------------------------------
__global__ __launch_bounds__(256) void attn_mfma(
    const u16* __restrict__ Qhp, const u16* __restrict__ Qlp,
    const u16* __restrict__ Kb,  const u16* __restrict__ Vt,
    u16* __restrict__ Yh, u16* __restrict__ Yl)
{
    __shared__ u16 Ks[64 * 128];   // 16 KiB
    __shared__ u16 Vs[128 * 64];   // 16 KiB
    __shared__ u16 Ps[4][16 * 64]; // 8 KiB (per-wave)

    const int tid = threadIdx.x;
    const int w = tid >> 6, ln = tid & 63;
    const int lo4 = ln & 15, hi4 = ln >> 4;
    const int qt = blockIdx.x, bh = blockIdx.y;
    const int q0 = qt * 64;

    // stage Q hi -> Ks area, Q lo -> Vs area (dead before first K/V stage)
    const size_t qoff = ((size_t)bh * TT + q0) * DD;
    #pragma unroll
    for (int i = 0; i < 4; ++i) {
        int L = i * 4096 + tid * 16;
        int r = L >> 8;
        int c = (L >> 4) & 15;
        int cs = c ^ (r & 7);
        gl_lds16(Qhp + qoff + r * DD + cs * 8, &Ks[L >> 1]);
        gl_lds16(Qlp + qoff + r * DD + cs * 8, &Vs[L >> 1]);
    }
    __syncthreads();
    bf8 qh[4], ql[4];
    {
        int r = w * 16 + lo4;
        #pragma unroll
        for (int ks = 0; ks < 4; ++ks) {
            int ch = (ks * 4 + hi4) ^ (r & 7);
            qh[ks] = *(const bf8*)&Ks[r * 128 + ch * 8];
            ql[ks] = *(const bf8*)&Vs[r * 128 + ch * 8];
        }
    }

    f32x4 O[8];
    #pragma unroll
    for (int i = 0; i < 8; ++i) O[i] = (f32x4){0.f, 0.f, 0.f, 0.f};
    float m_r[4] = {-1e30f, -1e30f, -1e30f, -1e30f};
    float l_r[4] = {0.f, 0.f, 0.f, 0.f};

    for (int kt = 0; kt <= qt; ++kt) {
        __syncthreads();   // prior readers done (incl. Q reg load on iter 0)
        const size_t koff = ((size_t)bh * TT + kt * 64) * DD;
        #pragma unroll
        for (int i = 0; i < 4; ++i) {
            int L = i * 4096 + tid * 16;
            int r = L >> 8;
            int c = (L >> 4) & 15;
            int cs = c ^ (r & 7);
            gl_lds16(Kb + koff + r * DD + cs * 8, &Ks[L >> 1]);
        }
        #pragma unroll
        for (int i = 0; i < 4; ++i) {
            int L = i * 4096 + tid * 16;
            int r = L >> 7;                       // d row (128 B rows)
            int c = (L >> 4) & 7;
            int cs = c ^ (r & 7);
            gl_lds16(Vt + ((size_t)bh * DD + r) * TT + kt * 64 + cs * 8, &Vs[L >> 1]);
        }
        __syncthreads();

        // S = (Qh+Ql) K^T  (scale folded into Q)
        f32x4 sf[4];
        #pragma unroll
        for (int nf = 0; nf < 4; ++nf) {
            f32x4 a2 = (f32x4){0.f, 0.f, 0.f, 0.f};
            int kr = nf * 16 + lo4;
            #pragma unroll
            for (int ks = 0; ks < 4; ++ks) {
                int ch = (ks * 4 + hi4) ^ (kr & 7);
                bf8 bb = *(const bf8*)&Ks[kr * 128 + ch * 8];
                a2 = MFMA(qh[ks], bb, a2);
                a2 = MFMA(ql[ks], bb, a2);
            }
            sf[nf] = a2;
        }
        if (kt == qt) {
            #pragma unroll
            for (int nf = 0; nf < 4; ++nf)
                #pragma unroll
                for (int r = 0; r < 4; ++r) {
                    int kg = kt * 64 + nf * 16 + lo4;
                    int qg = q0 + w * 16 + hi4 * 4 + r;
                    if (kg > qg) sf[nf][r] = -1e30f;
                }
        }
        // online softmax per row r
        #pragma unroll
        for (int r = 0; r < 4; ++r) {
            float mx = fmaxf(fmaxf(sf[0][r], sf[1][r]), fmaxf(sf[2][r], sf[3][r]));
            mx = fmaxf(mx, __shfl_xor(mx, 1));
            mx = fmaxf(mx, __shfl_xor(mx, 2));
            mx = fmaxf(mx, __shfl_xor(mx, 4));
            mx = fmaxf(mx, __shfl_xor(mx, 8));
            float mn = fmaxf(m_r[r], mx);
            float al = __expf(m_r[r] - mn);
            m_r[r] = mn;
            float rs = 0.f;
            #pragma unroll
            for (int nf = 0; nf < 4; ++nf) {
                float p = __expf(sf[nf][r] - mn);
                sf[nf][r] = p;
                rs += p;
            }
            rs += __shfl_xor(rs, 1);
            rs += __shfl_xor(rs, 2);
            rs += __shfl_xor(rs, 4);
            rs += __shfl_xor(rs, 8);
            l_r[r] = l_r[r] * al + rs;
            #pragma unroll
            for (int nf2 = 0; nf2 < 8; ++nf2) O[nf2][r] *= al;
        }
        // P -> bf16 -> per-wave swizzled LDS
        u16* pw = &Ps[w][0];
        #pragma unroll
        for (int r = 0; r < 4; ++r) {
            int row = hi4 * 4 + r;
            int sw = (row & 7) << 3;
            #pragma unroll
            for (int nf = 0; nf < 4; ++nf)
                pw[row * 64 + ((nf * 16 + lo4) ^ sw)] = f2bf(sf[nf][r]);
        }
        // O += P V
        bf8 pa[2];
        {
            int row = lo4, s3 = row & 7;
            pa[0] = *(const bf8*)&pw[row * 64 + ((hi4 ^ s3) * 8)];
            pa[1] = *(const bf8*)&pw[row * 64 + (((4 + hi4) ^ s3) * 8)];
        }
        #pragma unroll
        for (int nf2 = 0; nf2 < 8; ++nf2) {
            int vr = nf2 * 16 + lo4;
            #pragma unroll
            for (int ks = 0; ks < 2; ++ks) {
                int ch = (ks * 4 + hi4) ^ (vr & 7);
                bf8 vb = *(const bf8*)&Vs[vr * 64 + ch * 8];
                O[nf2] = MFMA(pa[ks], vb, O[nf2]);
            }
        }
    }

    // epilogue: y = O/l as bf16 hi/lo planes, row m = b*T+t, col = h*128+d
    const int b = bh >> 4, h = bh & 15;
    #pragma unroll
    for (int r = 0; r < 4; ++r) {
        float inv = 1.0f / l_r[r];
        int t = q0 + w * 16 + hi4 * 4 + r;
        size_t rowo = ((size_t)(b * TT + t)) * CC + h * DD;
        #pragma unroll
        for (int nf2 = 0; nf2 < 8; ++nf2) {
            float val = O[nf2][r] * inv;
            u16 hv = f2bf(val);
            Yh[rowo + nf2 * 16 + lo4] = hv;
            Yl[rowo + nf2 * 16 + lo4] = f2bf(val - bf2f(hv));
        }
    }
}

// ---------------------------------------------------------------------------
extern "C" void kernel_launch(void* const* d_in, const int* in_sizes, int n_in,
                              void* d_out, int out_size, void* d_ws, size_t ws_size,
                              hipStream_t stream)
{
    const float* X     = (const float*)d_in[0];
    const float* Wqkv  = (const float*)d_in[1];
    const float* Wproj = (const float*)d_in[2];

    char* W = (char*)d_ws;
    float* tab = (float*)W;                                   //   1 MiB
    u16* Wqh = (u16*)(W + (1u << 20));                        //  24 MiB
    u16* Wql = Wqh + 12582912;                                //  24 MiB
    u16* Wph = Wql + 12582912;                                //   8 MiB
    u16* Wpl = Wph + 4194304;                                 //   8 MiB
    u16* Xh  = Wpl + 4194304;                                 //  32 MiB
    u16* Xl  = Xh + 16777216;                                 //  32 MiB
    u16* Kb  = Xl + 16777216;                                 //  32 MiB
    u16* Vt  = Kb + 16777216;                                 //  32 MiB  (~193 MiB total)

    // Q hi/lo planes parked in d_out (dead before proj writes d_out)
    u16* Qh = (u16*)d_out;
    u16* Ql = Qh + 16777216;

    u16* Yh = Xh;   // y planes alias X planes (X dead after QKV gemm)
    u16* Yl = Xl;

    rope_tab_k<<<dim3(2048), 64, 0, stream>>>(tab);
    split_x_k<<<dim3(4096), 256, 0, stream>>>(X, Xh, Xl);
    splitT_k<<<dim3(32, 96), 256, 0, stream>>>(Wqkv, Wqh, Wql, 2048, 6144);
    splitT_k<<<dim3(32, 32), 256, 0, stream>>>(Wproj, Wph, Wpl, 2048, 2048);

    gemm3<0><<<dim3(64, 48), 256, 0, stream>>>(Xh, Xl, Wqh, Wql,
                                               Qh, Ql, Kb, Vt, tab, nullptr);
    attn_mfma<<<dim3(32, 64), 256, 0, stream>>>(Qh, Ql, Kb, Vt, Yh, Yl);
    gemm3<1><<<dim3(64, 16), 256, 0, stream>>>(Yh, Yl, Wph, Wpl,
                                               nullptr, nullptr, nullptr, nullptr,
                                               nullptr, (float*)d_out);
}

// Round 3
// 1230.564 us; speedup vs baseline: 5.0692x; 1.1414x over previous
//
#include <hip/hip_runtime.h>
#include <math.h>

#define NB 4
#define TT 2048
#define CC 2048
#define HH 16
#define DD 128
#define N3 6144
#define MM 8192   // NB*TT
#define BH 64     // NB*HH

typedef short bf8 __attribute__((ext_vector_type(8)));        // 8 bf16 (4 VGPR)
typedef float f32x4 __attribute__((ext_vector_type(4)));
typedef unsigned short u16x8 __attribute__((ext_vector_type(8)));
typedef unsigned short u16;

constexpr float SCALE_QK  = 0.08838834764831843f;   // 1/sqrt(128)
constexpr float NEG_ALPHA = -0.20503692777194262f;  // -2*ln(500000)/128

__device__ __forceinline__ u16 f2bf(float x) {                 // RTNE f32->bf16
    unsigned int u = __float_as_uint(x);
    u += 0x7fffu + ((u >> 16) & 1u);
    return (u16)(u >> 16);
}
__device__ __forceinline__ float bf2f(u16 h) { return __uint_as_float(((unsigned int)h) << 16); }

__device__ __forceinline__ void gl_lds16(const u16* g, u16* l) {
    __builtin_amdgcn_global_load_lds(reinterpret_cast<const unsigned int*>(g),
                                     reinterpret_cast<unsigned int*>(l), 16, 0, 0);
}
__device__ __forceinline__ f32x4 MFMA(bf8 a, bf8 b, f32x4 c) {
    return __builtin_amdgcn_mfma_f32_16x16x32_bf16(a, b, c, 0, 0, 0);
}

#define BAR()    __builtin_amdgcn_s_barrier()
#define SCHED0() __builtin_amdgcn_sched_barrier(0)
#define WAIT_LGKM0() do { asm volatile("s_waitcnt lgkmcnt(0)" ::: "memory"); SCHED0(); } while (0)
#define WAIT_VM4()   do { asm volatile("s_waitcnt vmcnt(4)"   ::: "memory"); SCHED0(); } while (0)
#define WAIT_VM0()   do { asm volatile("s_waitcnt vmcnt(0)"   ::: "memory"); SCHED0(); } while (0)

// ---------------------------------------------------------------------------
// RoPE table: tab[t][p] = {cos, sin}(t * base^(-2p/128)), 2048 x 64 x 2 f32.
// ---------------------------------------------------------------------------
__global__ void rope_tab_k(float* __restrict__ tab) {
    int t = blockIdx.x, p = threadIdx.x;
    float inv = expf((float)p * NEG_ALPHA);
    float s, c;
    sincosf((float)t * inv, &s, &c);
    tab[(t * 64 + p) * 2]     = c;
    tab[(t * 64 + p) * 2 + 1] = s;
}

// ---------------------------------------------------------------------------
// Elementwise split fp32 -> bf16 hi + bf16 lo (same layout).
// ---------------------------------------------------------------------------
__global__ __launch_bounds__(256) void split_x_k(const float* __restrict__ X,
                                                 u16* __restrict__ H, u16* __restrict__ L) {
    size_t base = ((size_t)blockIdx.x * 256 + threadIdx.x) * 16;
    #pragma unroll
    for (int g = 0; g < 2; ++g) {
        u16x8 hv, lv;
        #pragma unroll
        for (int j = 0; j < 8; j += 4) {
            float4 a = *(const float4*)(X + base + g * 8 + j);
            float xs[4] = {a.x, a.y, a.z, a.w};
            #pragma unroll
            for (int q = 0; q < 4; ++q) {
                u16 h = f2bf(xs[q]);
                hv[j + q] = h;
                lv[j + q] = f2bf(xs[q] - bf2f(h));
            }
        }
        *(u16x8*)&H[base + g * 8] = hv;
        *(u16x8*)&L[base + g * 8] = lv;
    }
}

// ---------------------------------------------------------------------------
// Split + transpose: W[Kd][Nd] fp32 -> OH/OL[Nd][Kd] bf16.
// ---------------------------------------------------------------------------
__global__ __launch_bounds__(256) void splitT_k(const float* __restrict__ W,
                                                u16* __restrict__ OH, u16* __restrict__ OL,
                                                int Kd, int Nd) {
    __shared__ float tile[64][68];
    int k0 = blockIdx.x * 64, n0 = blockIdx.y * 64;
    {
        int r = threadIdx.x >> 2, cg = threadIdx.x & 3;
        const float* src = W + (size_t)(k0 + r) * Nd + n0 + cg * 16;
        #pragma unroll
        for (int j = 0; j < 4; ++j)
            *(float4*)&tile[r][cg * 16 + j * 4] = *(const float4*)(src + j * 4);
    }
    __syncthreads();
    int nl = threadIdx.x >> 2, kg = threadIdx.x & 3;
    u16x8 hv[2], lv[2];
    #pragma unroll
    for (int j = 0; j < 16; ++j) {
        float v = tile[kg * 16 + j][nl];
        u16 h = f2bf(v);
        hv[j >> 3][j & 7] = h;
        lv[j >> 3][j & 7] = f2bf(v - bf2f(h));
    }
    size_t off = (size_t)(n0 + nl) * Kd + k0 + kg * 16;
    *(u16x8*)&OH[off]     = hv[0];
    *(u16x8*)&OH[off + 8] = hv[1];
    *(u16x8*)&OL[off]     = lv[0];
    *(u16x8*)&OL[off + 8] = lv[1];
}

// ---------------------------------------------------------------------------
// 8-phase 256x256 split-bf16 MFMA GEMM (T2+T3+T4+T5).
// Logical K = 6144 (3 planes: Ah*Bh + Al*Bh + Ah*Bl), BK=64, NKT=96 K-tiles.
// 512 thr = 8 waves (2M x 4N), per-wave 128x64 out, acc[8][4] f32x4.
// LDS: A/B double-buffered halves, 4 x 16KB each = 128 KiB, XOR-chunk swizzle
// via pre-swizzled global source (gl_lds dest linear).
// Staging stream s = K-tile*4 + {0:A0,1:A1,2:B0,3:B1}; during tile t phases
// issue s = 4t+6,4t+7,4t+8,4t+9; boundary wait vmcnt(4) (t=94: vmcnt(0)).
// MODE 0: QKV epilogue (RoPE; Q hi/lo planes, K bf16, V transposed [bh][d][t]).
// MODE 1: plain fp32 store.
// ---------------------------------------------------------------------------
template<int MODE>
__global__ __launch_bounds__(512, 2) void gemm8p(
    const u16* __restrict__ Ahp, const u16* __restrict__ Alp,
    const u16* __restrict__ Bhp, const u16* __restrict__ Blp,
    u16* __restrict__ Qh, u16* __restrict__ Ql,
    u16* __restrict__ Kbo, u16* __restrict__ Vto,
    const float* __restrict__ tab, float* __restrict__ Out)
{
    __shared__ u16 SM[66048];          // 129 KiB (GEMM uses first 65536)

    const int tid = threadIdx.x;
    const int w = tid >> 6, ln = tid & 63;
    const int lo4 = ln & 15, hi4 = ln >> 4;
    const int wr = w >> 2, wc = w & 3;          // 2 x 4 wave grid
    const int m0 = blockIdx.x * 256, n0 = blockIdx.y * 256;
    const int NKT = 96;

    f32x4 acc[8][4];
    #pragma unroll
    for (int i = 0; i < 8; ++i)
        #pragma unroll
        for (int j = 0; j < 4; ++j) acc[i][j] = (f32x4){0.f, 0.f, 0.f, 0.f};

    // ---- staging helper (2 x gl_lds per thread per half-tile) ----
    auto stage = [&](int s) {
        if (s >= 4 * NKT) return;
        const int tau = s >> 2, j = s & 3;
        const int c2 = tau & 1, op = j >> 1, hf = j & 1;
        const int tdiv = tau >> 5, tmod = tau & 31;
        const u16* plane;
        int row0;
        if (op == 0) { plane = (tdiv == 1) ? Alp : Ahp; row0 = m0 + hf * 128; }
        else         { plane = (tdiv == 2) ? Blp : Bhp; row0 = n0 + hf * 128; }
        u16* dst = SM + (op ? 32768 : 0) + (c2 * 2 + hf) * 8192;
        #pragma unroll
        for (int i = 0; i < 2; ++i) {
            int L = i * 8192 + tid * 16;     // byte offset within 16KB half
            int r = L >> 7;                  // row (128 B = 64 bf16 per row)
            int c = (L >> 4) & 7;
            int cs = c ^ (r & 7);            // pre-swizzled source chunk
            gl_lds16(plane + (size_t)(row0 + r) * 2048 + tmod * 64 + cs * 8,
                     dst + (L >> 1));
        }
    };

    // ---- prologue: tile0 (A0,A1,B0,B1) + tile1 (A0,A1) ----
    #pragma unroll
    for (int s = 0; s < 6; ++s) stage(s);
    WAIT_VM4();
    BAR();

    bf8 a03[4][2], a47[4][2], b01[2][2], b23[2][2];
    const int brow0 = (wc & 1) * 64;

    for (int t = 0; t < NKT; ++t) {
        const int c2 = t & 1;
        const u16* Ab = SM + (c2 * 2 + wr) * 8192;
        const u16* Bb = SM + 32768 + (c2 * 2 + (wc >> 1)) * 8192;

        // ---------- P1: read a[0:3], b[0:1]; stage t+1.B0 ----------
        #pragma unroll
        for (int mf = 0; mf < 4; ++mf) {
            int rr = mf * 16 + lo4, s7 = rr & 7;
            a03[mf][0] = *(const bf8*)&Ab[rr * 64 + ((hi4 ^ s7)) * 8];
            a03[mf][1] = *(const bf8*)&Ab[rr * 64 + (((4 + hi4) ^ s7)) * 8];
        }
        #pragma unroll
        for (int nf = 0; nf < 2; ++nf) {
            int rr = brow0 + nf * 16 + lo4, s7 = rr & 7;
            b01[nf][0] = *(const bf8*)&Bb[rr * 64 + ((hi4 ^ s7)) * 8];
            b01[nf][1] = *(const bf8*)&Bb[rr * 64 + (((4 + hi4) ^ s7)) * 8];
        }
        stage(4 * t + 6);
        BAR(); WAIT_LGKM0();
        __builtin_amdgcn_s_setprio(1);
        #pragma unroll
        for (int mf = 0; mf < 4; ++mf)
            #pragma unroll
            for (int nf = 0; nf < 2; ++nf) {
                acc[mf][nf] = MFMA(a03[mf][0], b01[nf][0], acc[mf][nf]);
                acc[mf][nf] = MFMA(a03[mf][1], b01[nf][1], acc[mf][nf]);
            }
        __builtin_amdgcn_s_setprio(0);
        BAR();

        // ---------- P2: read a[4:7]; stage t+1.B1 ----------
        #pragma unroll
        for (int mf = 0; mf < 4; ++mf) {
            int rr = 64 + mf * 16 + lo4, s7 = rr & 7;
            a47[mf][0] = *(const bf8*)&Ab[rr * 64 + ((hi4 ^ s7)) * 8];
            a47[mf][1] = *(const bf8*)&Ab[rr * 64 + (((4 + hi4) ^ s7)) * 8];
        }
        stage(4 * t + 7);
        BAR(); WAIT_LGKM0();
        __builtin_amdgcn_s_setprio(1);
        #pragma unroll
        for (int mf = 0; mf < 4; ++mf)
            #pragma unroll
            for (int nf = 0; nf < 2; ++nf) {
                acc[4 + mf][nf] = MFMA(a47[mf][0], b01[nf][0], acc[4 + mf][nf]);
                acc[4 + mf][nf] = MFMA(a47[mf][1], b01[nf][1], acc[4 + mf][nf]);
            }
        __builtin_amdgcn_s_setprio(0);
        BAR();

        // ---------- P3: read b[2:3]; stage t+2.A0 ----------
        #pragma unroll
        for (int nf = 0; nf < 2; ++nf) {
            int rr = brow0 + 32 + nf * 16 + lo4, s7 = rr & 7;
            b23[nf][0] = *(const bf8*)&Bb[rr * 64 + ((hi4 ^ s7)) * 8];
            b23[nf][1] = *(const bf8*)&Bb[rr * 64 + (((4 + hi4) ^ s7)) * 8];
        }
        stage(4 * t + 8);
        BAR(); WAIT_LGKM0();
        __builtin_amdgcn_s_setprio(1);
        #pragma unroll
        for (int mf = 0; mf < 4; ++mf)
            #pragma unroll
            for (int nf = 0; nf < 2; ++nf) {
                acc[mf][2 + nf] = MFMA(a03[mf][0], b23[nf][0], acc[mf][2 + nf]);
                acc[mf][2 + nf] = MFMA(a03[mf][1], b23[nf][1], acc[mf][2 + nf]);
            }
        __builtin_amdgcn_s_setprio(0);
        BAR();

        // ---------- P4: stage t+2.A1; boundary wait ----------
        stage(4 * t + 9);
        BAR();
        __builtin_amdgcn_s_setprio(1);
        #pragma unroll
        for (int mf = 0; mf < 4; ++mf)
            #pragma unroll
            for (int nf = 0; nf < 2; ++nf) {
                acc[4 + mf][2 + nf] = MFMA(a47[mf][0], b23[nf][0], acc[4 + mf][2 + nf]);
                acc[4 + mf][2 + nf] = MFMA(a47[mf][1], b23[nf][1], acc[4 + mf][2 + nf]);
            }
        __builtin_amdgcn_s_setprio(0);
        if (t < NKT - 2)       { WAIT_VM4(); }
        else if (t == NKT - 2) { WAIT_VM0(); }
        BAR();
    }

    // ======================= epilogues =======================
    if (MODE == 1) {
        #pragma unroll
        for (int mf = 0; mf < 8; ++mf)
            #pragma unroll
            for (int r = 0; r < 4; ++r) {
                int m = m0 + wr * 128 + mf * 16 + hi4 * 4 + r;
                float* rowp = Out + (size_t)m * CC + n0 + wc * 64;
                #pragma unroll
                for (int nf = 0; nf < 4; ++nf)
                    rowp[nf * 16 + lo4] = acc[mf][nf][r];
            }
        return;
    }

    // MODE 0: qkv epilogue. sec uniform per block (256-tile within a section).
    const int sec = n0 >> 11;                  // 0=q 1=k 2=v
    const int hh0 = (n0 >> 7) & 15;
    if (sec < 2) {
        #pragma unroll
        for (int mf = 0; mf < 8; ++mf)
            #pragma unroll
            for (int r = 0; r < 4; ++r) {
                int m = m0 + wr * 128 + mf * 16 + hi4 * 4 + r;
                int t = m & 2047, b = m >> 11;
                #pragma unroll
                for (int nf = 0; nf < 4; ++nf) {
                    int nl = wc * 64 + nf * 16 + lo4;
                    int h = hh0 + (nl >> 7), d = nl & 127;
                    float v = acc[mf][nf][r];
                    float o = __shfl_xor(v, 1);
                    const float2 cs2 = *(const float2*)&tab[(((size_t)t << 6) + (d >> 1)) * 2];
                    float rv = (ln & 1) ? (v * cs2.x + o * cs2.y)
                                        : (v * cs2.x - o * cs2.y);
                    size_t off = (((size_t)(b * HH + h)) * TT + t) * DD + d;
                    if (sec == 0) {
                        rv *= SCALE_QK;
                        u16 hv = f2bf(rv);
                        Qh[off] = hv;
                        Ql[off] = f2bf(rv - bf2f(hv));
                    } else {
                        Kbo[off] = f2bf(rv);
                    }
                }
            }
    } else {
        // V: bf16, transpose to [bh][d][t] via LDS [256][258] u16.
        BAR();
        #pragma unroll
        for (int mf = 0; mf < 8; ++mf)
            #pragma unroll
            for (int r = 0; r < 4; ++r) {
                int tl = wr * 128 + mf * 16 + hi4 * 4 + r;
                #pragma unroll
                for (int nf = 0; nf < 4; ++nf) {
                    int nl = wc * 64 + nf * 16 + lo4;
                    SM[tl * 258 + nl] = f2bf(acc[mf][nf][r]);
                }
            }
        BAR();
        int nl = tid >> 1, th = tid & 1;
        int head = hh0 + (nl >> 7), d = nl & 127;
        int b = m0 >> 11, t0 = m0 & 2047;
        size_t base = (((size_t)(b * HH + head)) * DD + d) * TT + t0 + th * 128;
        #pragma unroll
        for (int g = 0; g < 16; ++g) {
            u16x8 vv;
            #pragma unroll
            for (int j = 0; j < 8; ++j) vv[j] = SM[(th * 128 + g * 8 + j) * 258 + nl];
            *(u16x8*)&Vto[base + g * 8] = vv;
        }
    }
}

// ---------------------------------------------------------------------------
// Flash attention, bf16 MFMA (unchanged from round 2).
// ---------------------------------------------------------------------------
__global__ __launch_bounds__(256) void attn_mfma(
    const u16* __restrict__ Qhp, const u16* __restrict__ Qlp,
    const u16* __restrict__ Kb,  const u16* __restrict__ Vt,
    u16* __restrict__ Yh, u16* __restrict__ Yl)
{
    __shared__ u16 Ks[64 * 128];   // 16 KiB
    __shared__ u16 Vs[128 * 64];   // 16 KiB
    __shared__ u16 Ps[4][16 * 64]; // 8 KiB (per-wave)

    const int tid = threadIdx.x;
    const int w = tid >> 6, ln = tid & 63;
    const int lo4 = ln & 15, hi4 = ln >> 4;
    const int qt = blockIdx.x, bh = blockIdx.y;
    const int q0 = qt * 64;

    const size_t qoff = ((size_t)bh * TT + q0) * DD;
    #pragma unroll
    for (int i = 0; i < 4; ++i) {
        int L = i * 4096 + tid * 16;
        int r = L >> 8;
        int c = (L >> 4) & 15;
        int cs = c ^ (r & 7);
        gl_lds16(Qhp + qoff + r * DD + cs * 8, &Ks[L >> 1]);
        gl_lds16(Qlp + qoff + r * DD + cs * 8, &Vs[L >> 1]);
    }
    __syncthreads();
    bf8 qh[4], ql[4];
    {
        int r = w * 16 + lo4;
        #pragma unroll
        for (int ks = 0; ks < 4; ++ks) {
            int ch = (ks * 4 + hi4) ^ (r & 7);
            qh[ks] = *(const bf8*)&Ks[r * 128 + ch * 8];
            ql[ks] = *(const bf8*)&Vs[r * 128 + ch * 8];
        }
    }

    f32x4 O[8];
    #pragma unroll
    for (int i = 0; i < 8; ++i) O[i] = (f32x4){0.f, 0.f, 0.f, 0.f};
    float m_r[4] = {-1e30f, -1e30f, -1e30f, -1e30f};
    float l_r[4] = {0.f, 0.f, 0.f, 0.f};

    for (int kt = 0; kt <= qt; ++kt) {
        __syncthreads();
        const size_t koff = ((size_t)bh * TT + kt * 64) * DD;
        #pragma unroll
        for (int i = 0; i < 4; ++i) {
            int L = i * 4096 + tid * 16;
            int r = L >> 8;
            int c = (L >> 4) & 15;
            int cs = c ^ (r & 7);
            gl_lds16(Kb + koff + r * DD + cs * 8, &Ks[L >> 1]);
        }
        #pragma unroll
        for (int i = 0; i < 4; ++i) {
            int L = i * 4096 + tid * 16;
            int r = L >> 7;
            int c = (L >> 4) & 7;
            int cs = c ^ (r & 7);
            gl_lds16(Vt + ((size_t)bh * DD + r) * TT + kt * 64 + cs * 8, &Vs[L >> 1]);
        }
        __syncthreads();

        f32x4 sf[4];
        #pragma unroll
        for (int nf = 0; nf < 4; ++nf) {
            f32x4 a2 = (f32x4){0.f, 0.f, 0.f, 0.f};
            int kr = nf * 16 + lo4;
            #pragma unroll
            for (int ks = 0; ks < 4; ++ks) {
                int ch = (ks * 4 + hi4) ^ (kr & 7);
                bf8 bb = *(const bf8*)&Ks[kr * 128 + ch * 8];
                a2 = MFMA(qh[ks], bb, a2);
                a2 = MFMA(ql[ks], bb, a2);
            }
            sf[nf] = a2;
        }
        if (kt == qt) {
            #pragma unroll
            for (int nf = 0; nf < 4; ++nf)
                #pragma unroll
                for (int r = 0; r < 4; ++r) {
                    int kg = kt * 64 + nf * 16 + lo4;
                    int qg = q0 + w * 16 + hi4 * 4 + r;
                    if (kg > qg) sf[nf][r] = -1e30f;
                }
        }
        #pragma unroll
        for (int r = 0; r < 4; ++r) {
            float mx = fmaxf(fmaxf(sf[0][r], sf[1][r]), fmaxf(sf[2][r], sf[3][r]));
            mx = fmaxf(mx, __shfl_xor(mx, 1));
            mx = fmaxf(mx, __shfl_xor(mx, 2));
            mx = fmaxf(mx, __shfl_xor(mx, 4));
            mx = fmaxf(mx, __shfl_xor(mx, 8));
            float mn = fmaxf(m_r[r], mx);
            float al = __expf(m_r[r] - mn);
            m_r[r] = mn;
            float rs = 0.f;
            #pragma unroll
            for (int nf = 0; nf < 4; ++nf) {
                float p = __expf(sf[nf][r] - mn);
                sf[nf][r] = p;
                rs += p;
            }
            rs += __shfl_xor(rs, 1);
            rs += __shfl_xor(rs, 2);
            rs += __shfl_xor(rs, 4);
            rs += __shfl_xor(rs, 8);
            l_r[r] = l_r[r] * al + rs;
            #pragma unroll
            for (int nf2 = 0; nf2 < 8; ++nf2) O[nf2][r] *= al;
        }
        u16* pw = &Ps[w][0];
        #pragma unroll
        for (int r = 0; r < 4; ++r) {
            int row = hi4 * 4 + r;
            int sw = (row & 7) << 3;
            #pragma unroll
            for (int nf = 0; nf < 4; ++nf)
                pw[row * 64 + ((nf * 16 + lo4) ^ sw)] = f2bf(sf[nf][r]);
        }
        bf8 pa[2];
        {
            int row = lo4, s3 = row & 7;
            pa[0] = *(const bf8*)&pw[row * 64 + ((hi4 ^ s3) * 8)];
            pa[1] = *(const bf8*)&pw[row * 64 + (((4 + hi4) ^ s3) * 8)];
        }
        #pragma unroll
        for (int nf2 = 0; nf2 < 8; ++nf2) {
            int vr = nf2 * 16 + lo4;
            #pragma unroll
            for (int ks = 0; ks < 2; ++ks) {
                int ch = (ks * 4 + hi4) ^ (vr & 7);
                bf8 vb = *(const bf8*)&Vs[vr * 64 + ch * 8];
                O[nf2] = MFMA(pa[ks], vb, O[nf2]);
            }
        }
    }

    const int b = bh >> 4, h = bh & 15;
    #pragma unroll
    for (int r = 0; r < 4; ++r) {
        float inv = 1.0f / l_r[r];
        int t = q0 + w * 16 + hi4 * 4 + r;
        size_t rowo = ((size_t)(b * TT + t)) * CC + h * DD;
        #pragma unroll
        for (int nf2 = 0; nf2 < 8; ++nf2) {
            float val = O[nf2][r] * inv;
            u16 hv = f2bf(val);
            Yh[rowo + nf2 * 16 + lo4] = hv;
            Yl[rowo + nf2 * 16 + lo4] = f2bf(val - bf2f(hv));
        }
    }
}

// ---------------------------------------------------------------------------
extern "C" void kernel_launch(void* const* d_in, const int* in_sizes, int n_in,
                              void* d_out, int out_size, void* d_ws, size_t ws_size,
                              hipStream_t stream)
{
    const float* X     = (const float*)d_in[0];
    const float* Wqkv  = (const float*)d_in[1];
    const float* Wproj = (const float*)d_in[2];

    char* W = (char*)d_ws;
    float* tab = (float*)W;                                   //   1 MiB
    u16* Wqh = (u16*)(W + (1u << 20));                        //  24 MiB
    u16* Wql = Wqh + 12582912;                                //  24 MiB
    u16* Wph = Wql + 12582912;                                //   8 MiB
    u16* Wpl = Wph + 4194304;                                 //   8 MiB
    u16* Xh  = Wpl + 4194304;                                 //  32 MiB
    u16* Xl  = Xh + 16777216;                                 //  32 MiB
    u16* Kb  = Xl + 16777216;                                 //  32 MiB
    u16* Vt  = Kb + 16777216;                                 //  32 MiB  (~193 MiB total)

    u16* Qh = (u16*)d_out;          // parked in d_out (dead before proj writes)
    u16* Ql = Qh + 16777216;

    u16* Yh = Xh;   // y planes alias X planes (X dead after QKV gemm)
    u16* Yl = Xl;

    rope_tab_k<<<dim3(2048), 64, 0, stream>>>(tab);
    split_x_k<<<dim3(4096), 256, 0, stream>>>(X, Xh, Xl);
    splitT_k<<<dim3(32, 96), 256, 0, stream>>>(Wqkv, Wqh, Wql, 2048, 6144);
    splitT_k<<<dim3(32, 32), 256, 0, stream>>>(Wproj, Wph, Wpl, 2048, 2048);

    gemm8p<0><<<dim3(32, 24), 512, 0, stream>>>(Xh, Xl, Wqh, Wql,
                                                Qh, Ql, Kb, Vt, tab, nullptr);
    attn_mfma<<<dim3(32, 64), 256, 0, stream>>>(Qh, Ql, Kb, Vt, Yh, Yl);
    gemm8p<1><<<dim3(32, 8), 512, 0, stream>>>(Yh, Yl, Wph, Wpl,
                                               nullptr, nullptr, nullptr, nullptr,
                                               nullptr, (float*)d_out);
}

// Round 4
// 1016.728 us; speedup vs baseline: 6.1354x; 1.2103x over previous
//
#include <hip/hip_runtime.h>
#include <math.h>

#define NB 4
#define TT 2048
#define CC 2048
#define HH 16
#define DD 128
#define N3 6144
#define MM 8192   // NB*TT
#define BH 64     // NB*HH

typedef short bf8 __attribute__((ext_vector_type(8)));        // 8 bf16 (4 VGPR)
typedef float f32x4 __attribute__((ext_vector_type(4)));
typedef unsigned short u16x8 __attribute__((ext_vector_type(8)));
typedef unsigned short u16;

constexpr float SCALE_QK  = 0.08838834764831843f;   // 1/sqrt(128)
constexpr float NEG_ALPHA = -0.20503692777194262f;  // -2*ln(500000)/128

__device__ __forceinline__ u16 f2bf(float x) {                 // RTNE f32->bf16
    unsigned int u = __float_as_uint(x);
    u += 0x7fffu + ((u >> 16) & 1u);
    return (u16)(u >> 16);
}
__device__ __forceinline__ float bf2f(u16 h) { return __uint_as_float(((unsigned int)h) << 16); }

__device__ __forceinline__ void gl_lds16(const u16* g, u16* l) {
    __builtin_amdgcn_global_load_lds(reinterpret_cast<const unsigned int*>(g),
                                     reinterpret_cast<unsigned int*>(l), 16, 0, 0);
}
__device__ __forceinline__ f32x4 MFMA(bf8 a, bf8 b, f32x4 c) {
    return __builtin_amdgcn_mfma_f32_16x16x32_bf16(a, b, c, 0, 0, 0);
}

#define BAR()    __builtin_amdgcn_s_barrier()
#define SCHED0() __builtin_amdgcn_sched_barrier(0)
#define WAIT_LGKM0() do { asm volatile("s_waitcnt lgkmcnt(0)" ::: "memory"); SCHED0(); } while (0)
#define WAIT_VM8()   do { asm volatile("s_waitcnt vmcnt(8)"   ::: "memory"); SCHED0(); } while (0)
#define WAIT_VM4()   do { asm volatile("s_waitcnt vmcnt(4)"   ::: "memory"); SCHED0(); } while (0)
#define WAIT_VM0()   do { asm volatile("s_waitcnt vmcnt(0)"   ::: "memory"); SCHED0(); } while (0)

// ---------------------------------------------------------------------------
// RoPE table: tab[t][p] = {cos, sin}(t * base^(-2p/128)), 2048 x 64 x 2 f32.
// ---------------------------------------------------------------------------
__global__ void rope_tab_k(float* __restrict__ tab) {
    int t = blockIdx.x, p = threadIdx.x;
    float inv = expf((float)p * NEG_ALPHA);
    float s, c;
    sincosf((float)t * inv, &s, &c);
    tab[(t * 64 + p) * 2]     = c;
    tab[(t * 64 + p) * 2 + 1] = s;
}

// ---------------------------------------------------------------------------
// Elementwise split fp32 -> bf16 hi + bf16 lo (same layout).
// ---------------------------------------------------------------------------
__global__ __launch_bounds__(256) void split_x_k(const float* __restrict__ X,
                                                 u16* __restrict__ H, u16* __restrict__ L) {
    size_t base = ((size_t)blockIdx.x * 256 + threadIdx.x) * 16;
    #pragma unroll
    for (int g = 0; g < 2; ++g) {
        u16x8 hv, lv;
        #pragma unroll
        for (int j = 0; j < 8; j += 4) {
            float4 a = *(const float4*)(X + base + g * 8 + j);
            float xs[4] = {a.x, a.y, a.z, a.w};
            #pragma unroll
            for (int q = 0; q < 4; ++q) {
                u16 h = f2bf(xs[q]);
                hv[j + q] = h;
                lv[j + q] = f2bf(xs[q] - bf2f(h));
            }
        }
        *(u16x8*)&H[base + g * 8] = hv;
        *(u16x8*)&L[base + g * 8] = lv;
    }
}

// ---------------------------------------------------------------------------
// Transpose + bf16 (hi only): W[Kd][Nd] fp32 -> OH[Nd][Kd] bf16.
// ---------------------------------------------------------------------------
__global__ __launch_bounds__(256) void splitT_h(const float* __restrict__ W,
                                                u16* __restrict__ OH,
                                                int Kd, int Nd) {
    __shared__ float tile[64][68];
    int k0 = blockIdx.x * 64, n0 = blockIdx.y * 64;
    {
        int r = threadIdx.x >> 2, cg = threadIdx.x & 3;
        const float* src = W + (size_t)(k0 + r) * Nd + n0 + cg * 16;
        #pragma unroll
        for (int j = 0; j < 4; ++j)
            *(float4*)&tile[r][cg * 16 + j * 4] = *(const float4*)(src + j * 4);
    }
    __syncthreads();
    int nl = threadIdx.x >> 2, kg = threadIdx.x & 3;
    u16x8 hv[2];
    #pragma unroll
    for (int j = 0; j < 16; ++j)
        hv[j >> 3][j & 7] = f2bf(tile[kg * 16 + j][nl]);
    size_t off = (size_t)(n0 + nl) * Kd + k0 + kg * 16;
    *(u16x8*)&OH[off]     = hv[0];
    *(u16x8*)&OH[off + 8] = hv[1];
}

// ---------------------------------------------------------------------------
// 8-phase 256x256 split-bf16 MFMA GEMM, 2-pass: C = (Ah+Al)*Bh.
// Logical K = 4096 (2 A-planes x K=2048), BK=64, NKT=64 K-tiles.
// 512 thr = 8 waves (2M x 4N), per-wave 128x64 out, acc[8][4] f32x4.
// LDS: A/B double-buffered halves, 4 x 16KB = 128 KiB, chunk-XOR swizzle via
// pre-swizzled global source. Counted vmcnt(4) at K-tile boundary (T4).
// MODE 0: QKV epilogue (RoPE; Q hi/lo planes, K bf16, V transposed [bh][d][t]).
// MODE 1: plain fp32 store.
// ---------------------------------------------------------------------------
template<int MODE>
__global__ __launch_bounds__(512, 2) void gemm8p(
    const u16* __restrict__ Ahp, const u16* __restrict__ Alp,
    const u16* __restrict__ Bhp,
    u16* __restrict__ Qh, u16* __restrict__ Ql,
    u16* __restrict__ Kbo, u16* __restrict__ Vto,
    const float* __restrict__ tab, float* __restrict__ Out)
{
    __shared__ u16 SM[66048];          // 129 KiB (GEMM uses first 65536)

    const int tid = threadIdx.x;
    const int w = tid >> 6, ln = tid & 63;
    const int lo4 = ln & 15, hi4 = ln >> 4;
    const int wr = w >> 2, wc = w & 3;          // 2 x 4 wave grid
    const int m0 = blockIdx.x * 256, n0 = blockIdx.y * 256;
    const int NKT = 64;

    f32x4 acc[8][4];
    #pragma unroll
    for (int i = 0; i < 8; ++i)
        #pragma unroll
        for (int j = 0; j < 4; ++j) acc[i][j] = (f32x4){0.f, 0.f, 0.f, 0.f};

    // ---- staging: stream s = 4*tau + {0:A0,1:A1,2:B0,3:B1}, tau = K-tile ----
    auto stage = [&](int s) {
        if (s >= 4 * NKT) return;
        const int tau = s >> 2, j = s & 3;
        const int c2 = tau & 1, op = j >> 1, hf = j & 1;
        const int tdiv = tau >> 5, tmod = tau & 31;
        const u16* plane;
        int row0;
        if (op == 0) { plane = tdiv ? Alp : Ahp; row0 = m0 + hf * 128; }
        else         { plane = Bhp;              row0 = n0 + hf * 128; }
        u16* dst = SM + (op ? 32768 : 0) + (c2 * 2 + hf) * 8192;
        #pragma unroll
        for (int i = 0; i < 2; ++i) {
            int L = i * 8192 + tid * 16;     // byte offset within 16KB half
            int r = L >> 7;                  // row (128 B = 64 bf16 per row)
            int c = (L >> 4) & 7;
            int cs = c ^ (r & 7);            // pre-swizzled source chunk
            gl_lds16(plane + (size_t)(row0 + r) * 2048 + tmod * 64 + cs * 8,
                     dst + (L >> 1));
        }
    };

    #pragma unroll
    for (int s = 0; s < 6; ++s) stage(s);
    WAIT_VM4();
    BAR();

    bf8 a03[4][2], a47[4][2], b01[2][2], b23[2][2];
    const int brow0 = (wc & 1) * 64;

    for (int t = 0; t < NKT; ++t) {
        const int c2 = t & 1;
        const u16* Ab = SM + (c2 * 2 + wr) * 8192;
        const u16* Bb = SM + 32768 + (c2 * 2 + (wc >> 1)) * 8192;

        // ---------- P1: read a[0:3], b[0:1]; stage t+1.B0 ----------
        #pragma unroll
        for (int mf = 0; mf < 4; ++mf) {
            int rr = mf * 16 + lo4, s7 = rr & 7;
            a03[mf][0] = *(const bf8*)&Ab[rr * 64 + ((hi4 ^ s7)) * 8];
            a03[mf][1] = *(const bf8*)&Ab[rr * 64 + (((4 + hi4) ^ s7)) * 8];
        }
        #pragma unroll
        for (int nf = 0; nf < 2; ++nf) {
            int rr = brow0 + nf * 16 + lo4, s7 = rr & 7;
            b01[nf][0] = *(const bf8*)&Bb[rr * 64 + ((hi4 ^ s7)) * 8];
            b01[nf][1] = *(const bf8*)&Bb[rr * 64 + (((4 + hi4) ^ s7)) * 8];
        }
        stage(4 * t + 6);
        BAR(); WAIT_LGKM0();
        __builtin_amdgcn_s_setprio(1);
        #pragma unroll
        for (int mf = 0; mf < 4; ++mf)
            #pragma unroll
            for (int nf = 0; nf < 2; ++nf) {
                acc[mf][nf] = MFMA(a03[mf][0], b01[nf][0], acc[mf][nf]);
                acc[mf][nf] = MFMA(a03[mf][1], b01[nf][1], acc[mf][nf]);
            }
        __builtin_amdgcn_s_setprio(0);
        BAR();

        // ---------- P2: read a[4:7]; stage t+1.B1 ----------
        #pragma unroll
        for (int mf = 0; mf < 4; ++mf) {
            int rr = 64 + mf * 16 + lo4, s7 = rr & 7;
            a47[mf][0] = *(const bf8*)&Ab[rr * 64 + ((hi4 ^ s7)) * 8];
            a47[mf][1] = *(const bf8*)&Ab[rr * 64 + (((4 + hi4) ^ s7)) * 8];
        }
        stage(4 * t + 7);
        BAR(); WAIT_LGKM0();
        __builtin_amdgcn_s_setprio(1);
        #pragma unroll
        for (int mf = 0; mf < 4; ++mf)
            #pragma unroll
            for (int nf = 0; nf < 2; ++nf) {
                acc[4 + mf][nf] = MFMA(a47[mf][0], b01[nf][0], acc[4 + mf][nf]);
                acc[4 + mf][nf] = MFMA(a47[mf][1], b01[nf][1], acc[4 + mf][nf]);
            }
        __builtin_amdgcn_s_setprio(0);
        BAR();

        // ---------- P3: read b[2:3]; stage t+2.A0 ----------
        #pragma unroll
        for (int nf = 0; nf < 2; ++nf) {
            int rr = brow0 + 32 + nf * 16 + lo4, s7 = rr & 7;
            b23[nf][0] = *(const bf8*)&Bb[rr * 64 + ((hi4 ^ s7)) * 8];
            b23[nf][1] = *(const bf8*)&Bb[rr * 64 + (((4 + hi4) ^ s7)) * 8];
        }
        stage(4 * t + 8);
        BAR(); WAIT_LGKM0();
        __builtin_amdgcn_s_setprio(1);
        #pragma unroll
        for (int mf = 0; mf < 4; ++mf)
            #pragma unroll
            for (int nf = 0; nf < 2; ++nf) {
                acc[mf][2 + nf] = MFMA(a03[mf][0], b23[nf][0], acc[mf][2 + nf]);
                acc[mf][2 + nf] = MFMA(a03[mf][1], b23[nf][1], acc[mf][2 + nf]);
            }
        __builtin_amdgcn_s_setprio(0);
        BAR();

        // ---------- P4: stage t+2.A1; boundary wait ----------
        stage(4 * t + 9);
        BAR();
        __builtin_amdgcn_s_setprio(1);
        #pragma unroll
        for (int mf = 0; mf < 4; ++mf)
            #pragma unroll
            for (int nf = 0; nf < 2; ++nf) {
                acc[4 + mf][2 + nf] = MFMA(a47[mf][0], b23[nf][0], acc[4 + mf][2 + nf]);
                acc[4 + mf][2 + nf] = MFMA(a47[mf][1], b23[nf][1], acc[4 + mf][2 + nf]);
            }
        __builtin_amdgcn_s_setprio(0);
        if (t < NKT - 2)       { WAIT_VM4(); }
        else if (t == NKT - 2) { WAIT_VM0(); }
        BAR();
    }

    // ======================= epilogues =======================
    if (MODE == 1) {
        #pragma unroll
        for (int mf = 0; mf < 8; ++mf)
            #pragma unroll
            for (int r = 0; r < 4; ++r) {
                int m = m0 + wr * 128 + mf * 16 + hi4 * 4 + r;
                float* rowp = Out + (size_t)m * CC + n0 + wc * 64;
                #pragma unroll
                for (int nf = 0; nf < 4; ++nf)
                    rowp[nf * 16 + lo4] = acc[mf][nf][r];
            }
        return;
    }

    const int sec = n0 >> 11;                  // 0=q 1=k 2=v
    const int hh0 = (n0 >> 7) & 15;
    if (sec < 2) {
        #pragma unroll
        for (int mf = 0; mf < 8; ++mf)
            #pragma unroll
            for (int r = 0; r < 4; ++r) {
                int m = m0 + wr * 128 + mf * 16 + hi4 * 4 + r;
                int t = m & 2047, b = m >> 11;
                #pragma unroll
                for (int nf = 0; nf < 4; ++nf) {
                    int nl = wc * 64 + nf * 16 + lo4;
                    int h = hh0 + (nl >> 7), d = nl & 127;
                    float v = acc[mf][nf][r];
                    float o = __shfl_xor(v, 1);
                    const float2 cs2 = *(const float2*)&tab[(((size_t)t << 6) + (d >> 1)) * 2];
                    float rv = (ln & 1) ? (v * cs2.x + o * cs2.y)
                                        : (v * cs2.x - o * cs2.y);
                    size_t off = (((size_t)(b * HH + h)) * TT + t) * DD + d;
                    if (sec == 0) {
                        rv *= SCALE_QK;
                        u16 hv = f2bf(rv);
                        Qh[off] = hv;
                        Ql[off] = f2bf(rv - bf2f(hv));
                    } else {
                        Kbo[off] = f2bf(rv);
                    }
                }
            }
    } else {
        // V: bf16, transpose to [bh][d][t] via LDS [256][258] u16.
        BAR();
        #pragma unroll
        for (int mf = 0; mf < 8; ++mf)
            #pragma unroll
            for (int r = 0; r < 4; ++r) {
                int tl = wr * 128 + mf * 16 + hi4 * 4 + r;
                #pragma unroll
                for (int nf = 0; nf < 4; ++nf) {
                    int nl = wc * 64 + nf * 16 + lo4;
                    SM[tl * 258 + nl] = f2bf(acc[mf][nf][r]);
                }
            }
        BAR();
        int nl = tid >> 1, th = tid & 1;
        int head = hh0 + (nl >> 7), d = nl & 127;
        int b = m0 >> 11, t0 = m0 & 2047;
        size_t base = (((size_t)(b * HH + head)) * DD + d) * TT + t0 + th * 128;
        #pragma unroll
        for (int g = 0; g < 16; ++g) {
            u16x8 vv;
            #pragma unroll
            for (int j = 0; j < 8; ++j) vv[j] = SM[(th * 128 + g * 8 + j) * 258 + nl];
            *(u16x8*)&Vto[base + g * 8] = vv;
        }
    }
}

// ---------------------------------------------------------------------------
// Flash attention v2: QBLK=128, KVBLK=64, 4 waves x 32 q-rows.
// Double-buffered K/V with prefetch + counted vmcnt(8); defer-max (THR=0,
// bit-exact); Q hi/lo in regs (2x QK mfma); K/P/V bf16; fp32 online softmax.
// LDS 80 KiB -> 2 blocks/CU. Output y as bf16 hi/lo planes.
// ---------------------------------------------------------------------------
__global__ __launch_bounds__(256, 2) void attn128(
    const u16* __restrict__ Qhp, const u16* __restrict__ Qlp,
    const u16* __restrict__ Kb,  const u16* __restrict__ Vt,
    u16* __restrict__ Yh, u16* __restrict__ Yl)
{
    // u16 index map: K0 @0, K1 @8192, V0 @16384, V1 @24576, Ps @32768 (+w*2048)
    __shared__ u16 SM[40960];   // 80 KiB

    const int tid = threadIdx.x;
    const int w = tid >> 6, ln = tid & 63;
    const int lo4 = ln & 15, hi4 = ln >> 4;
    const int bx = blockIdx.x;
    const int qt = (bx & 1) ? (15 - (bx >> 1)) : (bx >> 1);   // pair big+small
    const int bh = blockIdx.y;
    const int q0 = qt * 128;
    const int last = 2 * qt + 1;

    // ---- stage Q hi -> SM[0..16384), Q lo -> SM[16384..32768) ----
    const size_t qoff = ((size_t)bh * TT + q0) * DD;
    #pragma unroll
    for (int i = 0; i < 8; ++i) {
        int L = i * 4096 + tid * 16;
        int r = L >> 8, c = (L >> 4) & 15;
        int cs = c ^ (r & 7);
        gl_lds16(Qhp + qoff + r * DD + cs * 8, &SM[L >> 1]);
        gl_lds16(Qlp + qoff + r * DD + cs * 8, &SM[16384 + (L >> 1)]);
    }
    WAIT_VM0();
    BAR();
    bf8 qh[2][4], ql[2][4];
    #pragma unroll
    for (int mf = 0; mf < 2; ++mf) {
        int rq = w * 32 + mf * 16 + lo4, s7 = rq & 7;
        #pragma unroll
        for (int ks = 0; ks < 4; ++ks) {
            int ch = (ks * 4 + hi4) ^ s7;
            qh[mf][ks] = *(const bf8*)&SM[rq * 128 + ch * 8];
            ql[mf][ks] = *(const bf8*)&SM[16384 + rq * 128 + ch * 8];
        }
    }
    WAIT_LGKM0();
    BAR();

    auto stageKV = [&](int kt2, int buf) {
        const size_t koff = ((size_t)bh * TT + kt2 * 64) * DD;
        u16* kd = &SM[buf * 8192];
        #pragma unroll
        for (int i = 0; i < 4; ++i) {
            int L = i * 4096 + tid * 16;
            int r = L >> 8, c = (L >> 4) & 15, cs = c ^ (r & 7);
            gl_lds16(Kb + koff + r * DD + cs * 8, kd + (L >> 1));
        }
        const size_t voff = (size_t)bh * DD * TT + (size_t)kt2 * 64;
        u16* vd = &SM[16384 + buf * 8192];
        #pragma unroll
        for (int i = 0; i < 4; ++i) {
            int L = i * 4096 + tid * 16;
            int r = L >> 7, c = (L >> 4) & 7, cs = c ^ (r & 7);
            gl_lds16(Vt + voff + (size_t)r * TT + cs * 8, vd + (L >> 1));
        }
    };
    stageKV(0, 0);

    f32x4 O[2][8];
    #pragma unroll
    for (int mf = 0; mf < 2; ++mf)
        #pragma unroll
        for (int i = 0; i < 8; ++i) O[mf][i] = (f32x4){0.f, 0.f, 0.f, 0.f};
    float m_r[2][4], l_r[2][4];
    #pragma unroll
    for (int mf = 0; mf < 2; ++mf)
        #pragma unroll
        for (int r = 0; r < 4; ++r) { m_r[mf][r] = -1e30f; l_r[mf][r] = 0.f; }

    for (int kt = 0; kt <= last; ++kt) {
        const int cur = kt & 1;
        if (kt < last) { stageKV(kt + 1, cur ^ 1); WAIT_VM8(); }
        else           { WAIT_VM0(); }
        BAR();
        const u16* Kcur = &SM[cur * 8192];
        const u16* Vcur = &SM[16384 + cur * 8192];

        // ---- S = (Qh+Ql) K^T (scale folded into Q) ----
        f32x4 sf[2][4];
        #pragma unroll
        for (int nf = 0; nf < 4; ++nf) {
            f32x4 s0 = (f32x4){0.f, 0.f, 0.f, 0.f};
            f32x4 s1 = (f32x4){0.f, 0.f, 0.f, 0.f};
            int kr = nf * 16 + lo4, s7 = kr & 7;
            #pragma unroll
            for (int ks = 0; ks < 4; ++ks) {
                bf8 bb = *(const bf8*)&Kcur[kr * 128 + ((ks * 4 + hi4) ^ s7) * 8];
                s0 = MFMA(qh[0][ks], bb, s0);
                s0 = MFMA(ql[0][ks], bb, s0);
                s1 = MFMA(qh[1][ks], bb, s1);
                s1 = MFMA(ql[1][ks], bb, s1);
            }
            sf[0][nf] = s0; sf[1][nf] = s1;
        }
        if (kt >= 2 * qt) {   // diagonal tiles: causal mask
            #pragma unroll
            for (int mf = 0; mf < 2; ++mf)
                #pragma unroll
                for (int nf = 0; nf < 4; ++nf)
                    #pragma unroll
                    for (int r = 0; r < 4; ++r) {
                        int kg = kt * 64 + nf * 16 + lo4;
                        int qg = q0 + w * 32 + mf * 16 + hi4 * 4 + r;
                        if (kg > qg) sf[mf][nf][r] = -1e30f;
                    }
        }

        // ---- online softmax with defer-max (THR=0: bit-exact skip) ----
        #pragma unroll
        for (int mf = 0; mf < 2; ++mf) {
            float mx[4];
            #pragma unroll
            for (int r = 0; r < 4; ++r) {
                float m2 = fmaxf(fmaxf(sf[mf][0][r], sf[mf][1][r]),
                                 fmaxf(sf[mf][2][r], sf[mf][3][r]));
                m2 = fmaxf(m2, __shfl_xor(m2, 1));
                m2 = fmaxf(m2, __shfl_xor(m2, 2));
                m2 = fmaxf(m2, __shfl_xor(m2, 4));
                m2 = fmaxf(m2, __shfl_xor(m2, 8));
                mx[r] = m2;
            }
            float al[4] = {1.f, 1.f, 1.f, 1.f};
            bool grow = (mx[0] > m_r[mf][0]) || (mx[1] > m_r[mf][1]) ||
                        (mx[2] > m_r[mf][2]) || (mx[3] > m_r[mf][3]);
            if (__any(grow)) {
                #pragma unroll
                for (int r = 0; r < 4; ++r) {
                    float mn = fmaxf(m_r[mf][r], mx[r]);
                    al[r] = __expf(m_r[mf][r] - mn);
                    m_r[mf][r] = mn;
                }
                #pragma unroll
                for (int nf2 = 0; nf2 < 8; ++nf2)
                    #pragma unroll
                    for (int r = 0; r < 4; ++r) O[mf][nf2][r] *= al[r];
            }
            #pragma unroll
            for (int r = 0; r < 4; ++r) {
                float rs = 0.f;
                #pragma unroll
                for (int nf = 0; nf < 4; ++nf) {
                    float p = __expf(sf[mf][nf][r] - m_r[mf][r]);
                    sf[mf][nf][r] = p;
                    rs += p;
                }
                rs += __shfl_xor(rs, 1);
                rs += __shfl_xor(rs, 2);
                rs += __shfl_xor(rs, 4);
                rs += __shfl_xor(rs, 8);
                l_r[mf][r] = l_r[mf][r] * al[r] + rs;
            }
        }

        // ---- P -> bf16 -> per-wave swizzled LDS; then O += P V ----
        u16* pw = &SM[32768 + w * 2048];
        #pragma unroll
        for (int mf = 0; mf < 2; ++mf)
            #pragma unroll
            for (int r = 0; r < 4; ++r) {
                int row = mf * 16 + hi4 * 4 + r;
                int sw = (row & 7) << 3;
                #pragma unroll
                for (int nf = 0; nf < 4; ++nf)
                    pw[row * 64 + ((nf * 16 + lo4) ^ sw)] = f2bf(sf[mf][nf][r]);
            }
        bf8 pa[2][2];
        #pragma unroll
        for (int mf = 0; mf < 2; ++mf) {
            int rp = mf * 16 + lo4, s3 = rp & 7;
            pa[mf][0] = *(const bf8*)&pw[rp * 64 + ((hi4 ^ s3) * 8)];
            pa[mf][1] = *(const bf8*)&pw[rp * 64 + (((4 + hi4) ^ s3) * 8)];
        }
        #pragma unroll
        for (int nf2 = 0; nf2 < 8; ++nf2) {
            int vr = nf2 * 16 + lo4, s7 = vr & 7;
            #pragma unroll
            for (int ks = 0; ks < 2; ++ks) {
                bf8 vb = *(const bf8*)&Vcur[vr * 64 + ((ks * 4 + hi4) ^ s7) * 8];
                O[0][nf2] = MFMA(pa[0][ks], vb, O[0][nf2]);
                O[1][nf2] = MFMA(pa[1][ks], vb, O[1][nf2]);
            }
        }
        BAR();   // all reads of buf[cur] done before next prefetch overwrites
    }

    // ---- epilogue: y = O/l as bf16 hi/lo planes ----
    const int b = bh >> 4, h = bh & 15;
    #pragma unroll
    for (int mf = 0; mf < 2; ++mf)
        #pragma unroll
        for (int r = 0; r < 4; ++r) {
            float inv = 1.0f / l_r[mf][r];
            int t = q0 + w * 32 + mf * 16 + hi4 * 4 + r;
            size_t rowo = ((size_t)(b * TT + t)) * CC + h * DD;
            #pragma unroll
            for (int nf2 = 0; nf2 < 8; ++nf2) {
                float val = O[mf][nf2][r] * inv;
                u16 hv = f2bf(val);
                Yh[rowo + nf2 * 16 + lo4] = hv;
                Yl[rowo + nf2 * 16 + lo4] = f2bf(val - bf2f(hv));
            }
        }
}

// ---------------------------------------------------------------------------
extern "C" void kernel_launch(void* const* d_in, const int* in_sizes, int n_in,
                              void* d_out, int out_size, void* d_ws, size_t ws_size,
                              hipStream_t stream)
{
    const float* X     = (const float*)d_in[0];
    const float* Wqkv  = (const float*)d_in[1];
    const float* Wproj = (const float*)d_in[2];

    char* W = (char*)d_ws;
    float* tab = (float*)W;                                   //   1 MiB
    u16* Wqh = (u16*)(W + (1u << 20));                        //  24 MiB
    u16* Wph = Wqh + 12582912;                                //   8 MiB
    u16* Xh  = Wph + 4194304;                                 //  32 MiB
    u16* Xl  = Xh + 16777216;                                 //  32 MiB
    u16* Kb  = Xl + 16777216;                                 //  32 MiB
    u16* Vt  = Kb + 16777216;                                 //  32 MiB  (~161 MiB)

    u16* Qh = (u16*)d_out;          // parked in d_out (dead before proj writes)
    u16* Ql = Qh + 16777216;

    u16* Yh = Xh;   // y planes alias X planes (X dead after QKV gemm)
    u16* Yl = Xl;

    rope_tab_k<<<dim3(2048), 64, 0, stream>>>(tab);
    split_x_k<<<dim3(4096), 256, 0, stream>>>(X, Xh, Xl);
    splitT_h<<<dim3(32, 96), 256, 0, stream>>>(Wqkv, Wqh, 2048, 6144);
    splitT_h<<<dim3(32, 32), 256, 0, stream>>>(Wproj, Wph, 2048, 2048);

    gemm8p<0><<<dim3(32, 24), 512, 0, stream>>>(Xh, Xl, Wqh,
                                                Qh, Ql, Kb, Vt, tab, nullptr);
    attn128<<<dim3(16, 64), 256, 0, stream>>>(Qh, Ql, Kb, Vt, Yh, Yl);
    gemm8p<1><<<dim3(32, 8), 512, 0, stream>>>(Yh, Yl, Wph,
                                               nullptr, nullptr, nullptr, nullptr,
                                               nullptr, (float*)d_out);
}